// Round 12
// baseline (309.572 us; speedup 1.0000x reference)
//
#include <hip/hip_runtime.h>
#include <cstdint>
#include <cstddef>

typedef _Float16 f16;
typedef _Float16 f16x8 __attribute__((ext_vector_type(8)));
typedef _Float16 f16x4 __attribute__((ext_vector_type(4)));
typedef float f32x4 __attribute__((ext_vector_type(4)));

#define AS1 __attribute__((address_space(1)))
#define AS3 __attribute__((address_space(3)))

__device__ __forceinline__ void gl_lds16(const void* g, void* l) {
    __builtin_amdgcn_global_load_lds((const AS1 uint32_t*)g, (AS3 uint32_t*)l, 16, 0, 0);
}

__device__ __forceinline__ f16x8 relu8(f16x8 x) {
    f16x8 z = {};
    return __builtin_elementwise_max(x, z);
}

// ===========================================================================
// 8-phase 256x256 GEMM (T2+T3+T4+T5 port) for C[M,512]=A[M,512]@W[512,512]^T
//   +bias. BK=64, 8 waves (2Mx4N), per-wave 128x64 out, acc[8][4] f32x4.
//   LDS 128KB: As/Bs[2 dbuf][2 half][128x64]. Per phase: 8 ds_read_b128 for
//   one (m-half,k-half) quadrant + stage one half-tile of kt+1 (2 gl_lds) +
//   16 MFMA in setprio(1). vmcnt(2) once per K-tile, never 0 mid-loop.
//   Swizzle: granule (row r, chunk c) at slot c^(r&7): even bank use on
//   ds_read_b128; gl_lds dest lane-linear, SOURCE permuted within the row's
//   128B line (involution; coalescing preserved). A staged at phases 0,1
//   (max latency slack); B (L2-hot W) at 2,3.
// ===========================================================================
__global__ __launch_bounds__(512, 2)
void gemm8p_kernel(const f16* __restrict__ A, const f16* __restrict__ W,
                   const float* __restrict__ bias, f16* __restrict__ C)
{
    __shared__ f16 As[2][2][8192];
    __shared__ f16 Bs[2][2][8192];
    const int tid = threadIdx.x;
    const int w = tid >> 6, lane = tid & 63;
    const int wm = w >> 2, wn = w & 3;
    const int lr = lane & 15, lk = lane >> 4;
    const int row0 = blockIdx.y << 8;
    const int col0 = blockIdx.x << 8;

    // staging: granules g1=tid, g2=tid+512 -> rows sr, sr+64; chunk sc (swz)
    const int sr = tid >> 3;
    const int sc = ((tid & 7) ^ (sr & 7)) << 3;
    const f16* Ast = A + (size_t)(row0 + sr) * 512 + sc;
    const f16* Wst = W + (size_t)(col0 + sr) * 512 + sc;

    const int sx0 = (lk ^ (lr & 7)) << 3;   // read slot offset, kh=0

    f32x4 acc[8][4] = {};

#define ST_HALF(DST, SRC, buf, h, kt)                                         \
    do {                                                                      \
        gl_lds16(SRC + (size_t)((h) * 128) * 512 + ((kt) << 6),               \
                 &DST[buf][h][(size_t)tid * 8]);                              \
        gl_lds16(SRC + (size_t)((h) * 128 + 64) * 512 + ((kt) << 6),          \
                 &DST[buf][h][((size_t)tid + 512) * 8]);                      \
    } while (0)

    // prologue: K-tile 0 -> buf 0 (8 loads)
    ST_HALF(As, Ast, 0, 0, 0);
    ST_HALF(As, Ast, 0, 1, 0);
    ST_HALF(Bs, Wst, 0, 0, 0);
    ST_HALF(Bs, Wst, 0, 1, 0);

    for (int kt = 0; kt < 8; ++kt) {
        const int buf = kt & 1;
        const f16* aH = &As[buf][wm][0];
        const f16* bH = &Bs[buf][wn >> 1][0];
#pragma unroll
        for (int q = 0; q < 4; ++q) {
            const int mh = q >> 1, kh = q & 1;
            if (kt < 7) {                      // stage half-tile q of kt+1
                if (q == 0)      ST_HALF(As, Ast, buf ^ 1, 0, kt + 1);
                else if (q == 1) ST_HALF(As, Ast, buf ^ 1, 1, kt + 1);
                else if (q == 2) ST_HALF(Bs, Wst, buf ^ 1, 0, kt + 1);
                else             ST_HALF(Bs, Wst, buf ^ 1, 1, kt + 1);
            }
            if (q == 0) {                      // K-tile boundary: kt ready?
                __builtin_amdgcn_sched_barrier(0);
                if (kt < 7) asm volatile("s_waitcnt vmcnt(2)" ::: "memory");
                else        asm volatile("s_waitcnt vmcnt(0)" ::: "memory");
                __builtin_amdgcn_s_barrier();
                __builtin_amdgcn_sched_barrier(0);
            }
            const int sx = sx0 ^ (kh << 5);
            f16x8 af[4], bf[4];
#pragma unroll
            for (int i = 0; i < 4; ++i)
                af[i] = *(const f16x8*)&aH[(mh * 64 + i * 16 + lr) * 64 + sx];
#pragma unroll
            for (int i = 0; i < 4; ++i)
                bf[i] = *(const f16x8*)&bH[((wn & 1) * 64 + i * 16 + lr) * 64 + sx];
            __builtin_amdgcn_s_setprio(1);
#pragma unroll
            for (int mi = 0; mi < 4; ++mi)
#pragma unroll
                for (int ni = 0; ni < 4; ++ni)
                    acc[mh * 4 + mi][ni] = __builtin_amdgcn_mfma_f32_16x16x32_f16(
                        af[mi], bf[ni], acc[mh * 4 + mi][ni], 0, 0, 0);
            __builtin_amdgcn_s_setprio(0);
            if (q == 3) __builtin_amdgcn_sched_barrier(0);
            __builtin_amdgcn_s_barrier();
        }
    }
#undef ST_HALF

    float bv[4];
#pragma unroll
    for (int ni = 0; ni < 4; ++ni)
        bv[ni] = bias[col0 + wn * 64 + ni * 16 + lr];
#pragma unroll
    for (int mi = 0; mi < 8; ++mi) {
#pragma unroll
        for (int ni = 0; ni < 4; ++ni) {
#pragma unroll
            for (int j = 0; j < 4; ++j) {
                int r = row0 + wm * 128 + mi * 16 + lk * 4 + j;
                int c = col0 + wn * 64 + ni * 16 + lr;
                C[(size_t)r * 512 + c] = (f16)(acc[mi][ni][j] + bv[ni]);
            }
        }
    }
}

// ===========================================================================
// XOR-slot swizzled 128x256 GEMM (r10/r11, conflict-free + coalesced).
// Used for PQ (K=128), ew3, nw1. launch_bounds MUST stay (256,2) (r9 spill).
// ===========================================================================
template<bool RELU>
__global__ __launch_bounds__(256, 2)
void gemm_swz_kernel(const f16* __restrict__ A, int lda,
                     const f16* __restrict__ W, int ldw,
                     const float* __restrict__ bias, float bscale,
                     f16* __restrict__ C, int ldc, int K)
{
    __shared__ f16 As[2][4096];
    __shared__ f16 Bs[2][8192];
    const int tid  = threadIdx.x;
    const int wave = tid >> 6, lane = tid & 63;
    const int wm = wave >> 1, wn = wave & 1;
    const int lr = lane & 15, lk = lane >> 4;
    const int row0 = blockIdx.y << 7;
    const int col0 = blockIdx.x << 8;

    const int c16 = (((tid & 3) ^ ((tid >> 3) & 3)) << 3);
    const f16* Ag = A + (size_t)(row0 + (tid >> 2)) * lda + c16;
    const f16* Wg = W + (size_t)(col0 + (tid >> 2)) * ldw + c16;
    const int kx = (lk ^ ((lr >> 1) & 3)) << 3;

    f32x4 acc[4][8] = {};

#define STAGE(buf, k0)                                                        \
    do {                                                                      \
        gl_lds16(Ag + (k0),                      &As[buf][tid * 8]);          \
        gl_lds16(Ag + (k0) + (size_t)64 * lda,   &As[buf][(tid + 256) * 8]);  \
        _Pragma("unroll")                                                     \
        for (int i_ = 0; i_ < 4; ++i_)                                        \
            gl_lds16(Wg + (k0) + (size_t)(i_ * 64) * ldw,                     \
                     &Bs[buf][(i_ * 256 + tid) * 8]);                         \
    } while (0)

    const int nt = K >> 5;
    STAGE(0, 0);
    for (int t = 0; t < nt; ++t) {
        const int cur = t & 1;
        if (t + 1 < nt) {
            STAGE(cur ^ 1, (t + 1) << 5);
            asm volatile("s_waitcnt vmcnt(6)" ::: "memory");
        } else {
            asm volatile("s_waitcnt vmcnt(0)" ::: "memory");
        }
        __builtin_amdgcn_s_barrier();
        __builtin_amdgcn_sched_barrier(0);

        f16x8 af[4], bf[8];
#pragma unroll
        for (int i = 0; i < 4; ++i)
            af[i] = *(const f16x8*)&As[cur][(wm * 64 + i * 16 + lr) * 32 + kx];
#pragma unroll
        for (int i = 0; i < 8; ++i)
            bf[i] = *(const f16x8*)&Bs[cur][(wn * 128 + i * 16 + lr) * 32 + kx];
#pragma unroll
        for (int mi = 0; mi < 4; ++mi)
#pragma unroll
            for (int ni = 0; ni < 8; ++ni)
                acc[mi][ni] = __builtin_amdgcn_mfma_f32_16x16x32_f16(
                    af[mi], bf[ni], acc[mi][ni], 0, 0, 0);

        __builtin_amdgcn_sched_barrier(0);
        __builtin_amdgcn_s_barrier();
    }
#undef STAGE

#pragma unroll
    for (int mi = 0; mi < 4; ++mi) {
#pragma unroll
        for (int ni = 0; ni < 8; ++ni) {
#pragma unroll
            for (int j = 0; j < 4; ++j) {
                int r = row0 + wm * 64 + mi * 16 + lk * 4 + j;
                int c = col0 + wn * 128 + ni * 16 + lr;
                float v = acc[mi][ni][j] + bias[c] * bscale;
                if (RELU) v = fmaxf(v, 0.0f);
                C[(size_t)r * ldc + c] = (f16)v;
            }
        }
    }
}

// ---------------------------------------------------------------------------
// Small GEMM (N=128; used once for nw3): 128x128 tile, legacy layout.
// ---------------------------------------------------------------------------
template<bool BIAS, bool RELU>
__global__ __launch_bounds__(256, 2)
void gemm_kernel(const f16* __restrict__ A, int lda,
                 const f16* __restrict__ W, int ldw,
                 const float* __restrict__ bias, float bscale,
                 f16* __restrict__ C, int ldc, int K)
{
    __shared__ f16 As[4096];
    __shared__ f16 Bs[4096];
    const int tid  = threadIdx.x;
    const int wave = tid >> 6;
    const int lane = tid & 63;
    const int wm = wave >> 1, wn = wave & 1;
    const int lr = lane & 15, lk = lane >> 4;
    const int row0 = blockIdx.y << 7;
    const int col0 = blockIdx.x << 7;

    const int srow = tid >> 2;
    const int scol = (tid & 3) << 3;
    const f16* Ag = A + (size_t)(row0 + srow) * lda + scol;
    const f16* Wg = W + (size_t)(col0 + srow) * ldw + scol;
    f16* lA0 = &As[wave * 512];
    f16* lA1 = &As[2048 + wave * 512];
    f16* lB0 = &Bs[wave * 512];
    f16* lB1 = &Bs[2048 + wave * 512];

    f32x4 acc[4][4] = {};

    for (int k0 = 0; k0 < K; k0 += 32) {
        if (k0) __syncthreads();
        gl_lds16(Ag + k0,                    lA0);
        gl_lds16(Ag + k0 + (size_t)64 * lda, lA1);
        gl_lds16(Wg + k0,                    lB0);
        gl_lds16(Wg + k0 + (size_t)64 * ldw, lB1);
        __syncthreads();

        f16x8 af[4], bf[4];
#pragma unroll
        for (int i = 0; i < 4; ++i)
            af[i] = *(const f16x8*)&As[(wm * 64 + i * 16 + lr) * 32 + lk * 8];
#pragma unroll
        for (int i = 0; i < 4; ++i)
            bf[i] = *(const f16x8*)&Bs[(wn * 64 + i * 16 + lr) * 32 + lk * 8];
#pragma unroll
        for (int mi = 0; mi < 4; ++mi)
#pragma unroll
            for (int ni = 0; ni < 4; ++ni)
                acc[mi][ni] = __builtin_amdgcn_mfma_f32_16x16x32_f16(
                    af[mi], bf[ni], acc[mi][ni], 0, 0, 0);
    }

#pragma unroll
    for (int mi = 0; mi < 4; ++mi) {
#pragma unroll
        for (int ni = 0; ni < 4; ++ni) {
#pragma unroll
            for (int j = 0; j < 4; ++j) {
                int r = row0 + wm * 64 + mi * 16 + lk * 4 + j;
                int c = col0 + wn * 64 + ni * 16 + lr;
                float v = acc[mi][ni][j];
                if (BIAS) v += bias[c] * bscale;
                if (RELU) v = fmaxf(v, 0.0f);
                C[(size_t)r * ldc + c] = (f16)v;
            }
        }
    }
}

// ---------------------------------------------------------------------------
// expand: E1[row,:] = relu(P[b*8+r,:] + Q[b*8+cn,:]); P/Q packed in PQ
// [node][1024] (P cols 0:512, Q cols 512:1024; 0.5*eb1 folded into both).
// ---------------------------------------------------------------------------
__global__ void expand_kernel(const f16* __restrict__ PQ, f16* __restrict__ E1)
{
    int idx = blockIdx.x * 256 + threadIdx.x;    // RE*64 total
    int row = idx >> 6;
    int c8  = (idx & 63) << 3;
    int b = row / 56;
    int e = row - b * 56;
    int r = e / 7;
    int t = e - r * 7;
    int cn = t + (t >= r ? 1 : 0);
    f16x8 p = *(const f16x8*)&PQ[((size_t)(b * 8 + r)  << 10) + c8];
    f16x8 q = *(const f16x8*)&PQ[((size_t)(b * 8 + cn) << 10) + 512 + c8];
    *(f16x8*)&E1[((size_t)row << 9) + c8] = relu8(p + q);
}

// ---------------------------------------------------------------------------
// Fused GEMM + bias + LayerNorm + relu (node MLP layer 2). BM=64, 8 waves,
// K=512, W row-stride 512. XOR-slot swizzled staging (coalesced).
// ---------------------------------------------------------------------------
__global__ __launch_bounds__(512, 2)
void fused_gemm_ln(const f16* __restrict__ A, int lda,
                   const f16* __restrict__ W,
                   const float* __restrict__ bias,
                   const float* __restrict__ g, const float* __restrict__ b,
                   f16* __restrict__ C, int ldc)
{
    constexpr int BM = 64, NI = 4, NWN = 8;
    __shared__ f16 As[BM * 32];
    __shared__ f16 Bs[512 * 32];
    __shared__ float lnred[BM * NWN * 2];
    __shared__ float stat[BM * 2];

    const int tid  = threadIdx.x;
    const int wave = tid >> 6;
    const int lane = tid & 63;
    const int wn = wave;
    const int lr = lane & 15, lk = lane >> 4;
    const int row0 = blockIdx.x * BM;
    const int wcol0 = wn * (NI * 16);

    const int c16 = (((tid & 3) ^ ((tid >> 3) & 3)) << 3);
    const f16* Ar = A + (size_t)(row0 + (tid >> 2)) * lda + c16;
    const f16* Wr = W + (size_t)(tid >> 2) * 512 + c16;
    const int kx = (lk ^ ((lr >> 1) & 3)) << 3;

    f32x4 acc[4][NI] = {};

    for (int k0 = 0; k0 < 512; k0 += 32) {
        if (k0) __syncthreads();
#pragma unroll
        for (int i = 0; i < 4; ++i)
            gl_lds16(Wr + k0 + (size_t)(i * 128) * 512, &Bs[(i * 512 + tid) * 8]);
        if (tid < 256)
            gl_lds16(Ar + k0, &As[tid * 8]);
        __syncthreads();

        f16x8 af[4], bf[NI];
#pragma unroll
        for (int i = 0; i < 4; ++i)
            af[i] = *(const f16x8*)&As[(i * 16 + lr) * 32 + kx];
#pragma unroll
        for (int i = 0; i < NI; ++i)
            bf[i] = *(const f16x8*)&Bs[(wcol0 + i * 16 + lr) * 32 + kx];
#pragma unroll
        for (int mi = 0; mi < 4; ++mi)
#pragma unroll
            for (int ni = 0; ni < NI; ++ni)
                acc[mi][ni] = __builtin_amdgcn_mfma_f32_16x16x32_f16(
                    af[mi], bf[ni], acc[mi][ni], 0, 0, 0);
    }

    float biasv[NI], gv[NI], bv[NI];
#pragma unroll
    for (int ni = 0; ni < NI; ++ni) {
        int col = wcol0 + ni * 16 + lr;
        biasv[ni] = bias[col];
        gv[ni] = g[col];
        bv[ni] = b[col];
    }
#pragma unroll
    for (int mi = 0; mi < 4; ++mi)
#pragma unroll
        for (int ni = 0; ni < NI; ++ni)
#pragma unroll
            for (int j = 0; j < 4; ++j)
                acc[mi][ni][j] += biasv[ni];

#pragma unroll
    for (int mi = 0; mi < 4; ++mi) {
#pragma unroll
        for (int j = 0; j < 4; ++j) {
            float s = 0.f, s2 = 0.f;
#pragma unroll
            for (int ni = 0; ni < NI; ++ni) {
                float v = acc[mi][ni][j];
                s += v; s2 += v * v;
            }
#pragma unroll
            for (int o = 1; o < 16; o <<= 1) {
                s  += __shfl_xor(s,  o, 64);
                s2 += __shfl_xor(s2, o, 64);
            }
            if (lr == 0) {
                int row = mi * 16 + lk * 4 + j;
                lnred[(row * NWN + wn) * 2 + 0] = s;
                lnred[(row * NWN + wn) * 2 + 1] = s2;
            }
        }
    }
    __syncthreads();
    if (tid < BM) {
        float s = 0.f, s2 = 0.f;
#pragma unroll
        for (int w = 0; w < NWN; ++w) {
            s  += lnred[(tid * NWN + w) * 2 + 0];
            s2 += lnred[(tid * NWN + w) * 2 + 1];
        }
        float mean = s * (1.0f / 512.0f);
        float var  = fmaxf(s2 * (1.0f / 512.0f) - mean * mean, 0.0f);
        stat[tid * 2 + 0] = mean;
        stat[tid * 2 + 1] = rsqrtf(var + 1e-5f);
    }
    __syncthreads();

#pragma unroll
    for (int mi = 0; mi < 4; ++mi) {
#pragma unroll
        for (int j = 0; j < 4; ++j) {
            int row = mi * 16 + lk * 4 + j;
            float mean = stat[row * 2 + 0];
            float rstd = stat[row * 2 + 1];
            size_t gr = (size_t)(row0 + row) * ldc;
#pragma unroll
            for (int ni = 0; ni < NI; ++ni) {
                float y = (acc[mi][ni][j] - mean) * rstd * gv[ni] + bv[ni];
                C[gr + wcol0 + ni * 16 + lr] = (f16)fmaxf(y, 0.0f);
            }
        }
    }
}

// ---------------------------------------------------------------------------
// Convert fp32 -> f16. Slots strided into XCAT cols 0:128 (ldc=640).
// ew1 repacked: w_ew1x[1024][128] = [ew1[:, :128] ; ew1[:, 128:]].
// eb1x[1024] f32 = 0.5*[eb1 ; eb1].
// ---------------------------------------------------------------------------
__global__ void convert_all_kernel(
    const float* __restrict__ s0, f16* __restrict__ xcat,
    const float* __restrict__ s1, f16* __restrict__ d1,
    const float* __restrict__ s2, f16* __restrict__ d2,
    const float* __restrict__ s3, f16* __restrict__ d3,
    const float* __restrict__ s4, f16* __restrict__ d4,
    const float* __restrict__ s5, f16* __restrict__ d5,
    const float* __restrict__ s6, f16* __restrict__ d6,
    const float* __restrict__ eb1, float* __restrict__ eb1x)
{
    int q = blockIdx.x * 256 + threadIdx.x;
    if (q >= 852224) return;
    if (q < 524288) {
        const float4 v = *(const float4*)&s0[(size_t)q * 4];
        f16x4 o; o[0]=(f16)v.x; o[1]=(f16)v.y; o[2]=(f16)v.z; o[3]=(f16)v.w;
        int row = q >> 5, col = (q & 31) << 2;
        *(f16x4*)&xcat[(size_t)row * 640 + col] = o;
        return;
    }
    if (q >= 851968) {
        int i = q - 851968;
        int srcq = (i < 128) ? i : i - 128;
        const float4 v = *(const float4*)&eb1[srcq * 4];
        float4 o; o.x = 0.5f*v.x; o.y = 0.5f*v.y; o.z = 0.5f*v.z; o.w = 0.5f*v.w;
        *(float4*)&eb1x[i * 4] = o;
        return;
    }
    if (q < 557056) {
        int i = q - 524288;
        int f = i << 2;
        int n = f >> 8, c = f & 255;
        const float4 v = *(const float4*)&s1[(size_t)f];
        f16x4 o; o[0]=(f16)v.x; o[1]=(f16)v.y; o[2]=(f16)v.z; o[3]=(f16)v.w;
        int dst = (c < 128) ? n * 128 + c : (512 + n) * 128 + (c - 128);
        *(f16x4*)&d1[dst] = o;
        return;
    }
    const float* s; f16* d; int i;
    if      (q < 622592) { s = s2; d = d2; i = q - 557056; }
    else if (q < 688128) { s = s3; d = d3; i = q - 622592; }
    else if (q < 770048) { s = s4; d = d4; i = q - 688128; }
    else if (q < 835584) { s = s5; d = d5; i = q - 770048; }
    else                 { s = s6; d = d6; i = q - 835584; }
    const float4 v = *(const float4*)&s[(size_t)i * 4];
    f16x4 o; o[0]=(f16)v.x; o[1]=(f16)v.y; o[2]=(f16)v.z; o[3]=(f16)v.w;
    *(f16x4*)&d[(size_t)i * 4] = o;
}

// ---------------------------------------------------------------------------
// ln_agg: AGG[node,:] = sum_{t<7} relu(LN(E2[node*7+t,:])*g+b). 1 wave/node.
// ---------------------------------------------------------------------------
__global__ void ln_agg_kernel(const f16* __restrict__ E2,
                              const float* __restrict__ g, const float* __restrict__ b,
                              f16* __restrict__ AGG, int nodes)
{
    int gw   = (blockIdx.x * 256 + threadIdx.x) >> 6;
    int lane = threadIdx.x & 63;
    if (gw >= nodes) return;
    int bb = gw >> 3, n = gw & 7;
    const f16* base = E2 + (((size_t)(bb * 56 + n * 7)) << 9) + (lane << 3);
    f16x8 v[7];
#pragma unroll
    for (int t = 0; t < 7; ++t) v[t] = *(const f16x8*)(base + ((size_t)t << 9));
    float gv[8], bv[8], acc[8] = {};
#pragma unroll
    for (int j = 0; j < 8; ++j) {
        gv[j] = g[(lane << 3) + j];
        bv[j] = b[(lane << 3) + j];
    }
#pragma unroll
    for (int t = 0; t < 7; ++t) {
        float f[8]; float s = 0.f, s2 = 0.f;
#pragma unroll
        for (int j = 0; j < 8; ++j) { f[j] = (float)v[t][j]; s += f[j]; s2 += f[j] * f[j]; }
#pragma unroll
        for (int o = 32; o; o >>= 1) { s += __shfl_xor(s, o, 64); s2 += __shfl_xor(s2, o, 64); }
        float mean = s * (1.0f / 512.0f);
        float var  = fmaxf(s2 * (1.0f / 512.0f) - mean * mean, 0.0f);
        float rstd = rsqrtf(var + 1e-5f);
#pragma unroll
        for (int j = 0; j < 8; ++j)
            acc[j] += fmaxf((f[j] - mean) * rstd * gv[j] + bv[j], 0.0f);
    }
    f16x8 o;
#pragma unroll
    for (int j = 0; j < 8; ++j) o[j] = (f16)acc[j];
    *(f16x8*)&AGG[((size_t)gw << 9) + (lane << 3)] = o;
}

// ---------------------------------------------------------------------------
// out[b,:] = (sum_n x3[b,n,:]) @ head_w^T + head_b
// ---------------------------------------------------------------------------
__global__ void head_kernel(const f16* __restrict__ x3, const float* __restrict__ hw,
                            const float* __restrict__ hb, float* __restrict__ out)
{
    __shared__ float pooled[128];
    int b = blockIdx.x, t = threadIdx.x;   // 128 threads
    float s = 0.f;
#pragma unroll
    for (int n = 0; n < 8; ++n) s += (float)x3[(((size_t)b * 8 + n) << 7) + t];
    pooled[t] = s;
    __syncthreads();
    if (t < 12) {
        float acc = hb[t];
        for (int d = 0; d < 128; ++d) acc += pooled[d] * hw[t * 128 + d];
        out[b * 12 + t] = acc;
    }
}

// ---------------------------------------------------------------------------
extern "C" void kernel_launch(void* const* d_in, const int* in_sizes, int n_in,
                              void* d_out, int out_size, void* d_ws, size_t ws_size,
                              hipStream_t stream)
{
    const float* slots  = (const float*)d_in[0];
    const float* ew1    = (const float*)d_in[1];
    const float* eb1    = (const float*)d_in[2];
    const float* ew2    = (const float*)d_in[3];
    const float* eb2    = (const float*)d_in[4];
    const float* eln_g  = (const float*)d_in[5];
    const float* eln_b  = (const float*)d_in[6];
    const float* ew3    = (const float*)d_in[7];
    const float* eb3    = (const float*)d_in[8];
    const float* nw1    = (const float*)d_in[9];
    const float* nb1    = (const float*)d_in[10];
    const float* nw2    = (const float*)d_in[11];
    const float* nb2    = (const float*)d_in[12];
    const float* nln_g  = (const float*)d_in[13];
    const float* nln_b  = (const float*)d_in[14];
    const float* nw3    = (const float*)d_in[15];
    const float* nb3    = (const float*)d_in[16];
    const float* head_w = (const float*)d_in[17];
    const float* head_b = (const float*)d_in[18];

    char* ws = (char*)d_ws;
    f16*   XCAT    = (f16*)(ws + 0);            // 20,971,520
    f16*   w_ew1x  = (f16*)(ws + 20971520);     //   262,144  [1024][128]
    f16*   w_ew2   = (f16*)(ws + 21233664);     //   524,288
    f16*   w_ew3   = (f16*)(ws + 21757952);     //   524,288
    f16*   w_nw1   = (f16*)(ws + 22282240);     //   655,360
    f16*   w_nw2   = (f16*)(ws + 22937600);     //   524,288
    f16*   w_nw3   = (f16*)(ws + 23461888);     //   131,072
    float* eb1x    = (float*)(ws + 23592960);   //     4,096  [1024] f32
    f16*   AGG     = (f16*)(ws + 23597056);     // 16,777,216
    char*  arena   =        ws + 40374272;      // 131072*BCH bytes

    const size_t FIXED = 40374272ULL;
    int BCH;
    if      (ws_size >= FIXED + 131072ULL * 1024) BCH = 1024;  // 174.6 MB
    else if (ws_size >= FIXED + 131072ULL * 512)  BCH = 512;   // 107.5 MB
    else                                          BCH = 256;   //  74.0 MB
    const int nch = 2048 / BCH;
    const int RN  = BCH * 8;    // node rows / chunk (mult 128)
    const int RE  = BCH * 56;   // edge rows / chunk (mult 256)

    f16* PQc = (f16*)(arena);                                  // 16384*BCH B
    f16* E1c = (f16*)(arena + (size_t)16384 * BCH);            // 57344*BCH B
    f16* E2c = (f16*)(arena + (size_t)73728 * BCH);            // 57344*BCH B

    f16* X1 = AGG;
    f16* X2 = (f16*)(arena);
    f16* X3 = (f16*)(arena + 16777216);
    float* out = (float*)d_out;

    convert_all_kernel<<<dim3(3329), 256, 0, stream>>>(
        slots, XCAT, ew1, w_ew1x, ew2, w_ew2, ew3, w_ew3,
        nw1, w_nw1, nw2, w_nw2, nw3, w_nw3, eb1, eb1x);

    for (int c = 0; c < nch; ++c) {
        const f16* sc = XCAT + (size_t)c * RN * 640;
        // PQ = slots @ [ew1_P; ew1_Q]^T + 0.5*[eb1;eb1]   (one N=1024 GEMM)
        gemm_swz_kernel<false><<<dim3(4, RN/128), 256, 0, stream>>>(
            sc, 640, w_ew1x, 128, eb1x, 1.0f, PQc, 1024, 128);
        // e1 = relu(P[src] + Q[tgt])
        expand_kernel<<<dim3(RE/4), 256, 0, stream>>>(PQc, E1c);
        // e2 = e1 @ ew2^T + eb2   (8-phase 256^2 schedule)
        gemm8p_kernel<<<dim3(2, RE/256), 512, 0, stream>>>(E1c, w_ew2, eb2, E2c);
        // agg = segsum(relu(LN(e2)))
        ln_agg_kernel<<<dim3(RN/4), 256, 0, stream>>>(
            E2c, eln_g, eln_b, AGG + (size_t)c * RN * 512, RN);
    }

    // xcat[:,128:640] = AGG @ ew3^T + 7*eb3   (linearity of segment-sum)
    gemm_swz_kernel<false><<<dim3(2,128), 256, 0, stream>>>(
        AGG, 512, w_ew3, 512, eb3, 7.0f, XCAT + 128, 640, 512);
    // x1 = relu(xcat @ nw1^T + nb1)
    gemm_swz_kernel<true><<<dim3(2,128), 256, 0, stream>>>(
        XCAT, 640, w_nw1, 640, nb1, 1.0f, X1, 512, 640);
    // x2 = relu(LN(x1 @ nw2^T + nb2))
    fused_gemm_ln<<<dim3(256), 512, 0, stream>>>(
        X1, 512, w_nw2, nb2, nln_g, nln_b, X2, 512);
    // x3 = relu(x2 @ nw3^T + nb3)
    gemm_kernel<true,true><<<dim3(1,128), 256, 0, stream>>>(
        X2, 512, w_nw3, 512, nb3, 1.0f, X3, 128, 512);

    head_kernel<<<dim3(2048), 128, 0, stream>>>(X3, head_w, head_b, out);
}

// Round 13
// 220.300 us; speedup vs baseline: 1.4052x; 1.4052x over previous
//
#include <hip/hip_runtime.h>
#include <cstdint>
#include <cstddef>

typedef _Float16 f16;
typedef _Float16 f16x8 __attribute__((ext_vector_type(8)));
typedef _Float16 f16x4 __attribute__((ext_vector_type(4)));
typedef float f32x4 __attribute__((ext_vector_type(4)));

#define AS1 __attribute__((address_space(1)))
#define AS3 __attribute__((address_space(3)))

__device__ __forceinline__ void gl_lds16(const void* g, void* l) {
    __builtin_amdgcn_global_load_lds((const AS1 uint32_t*)g, (AS3 uint32_t*)l, 16, 0, 0);
}

__device__ __forceinline__ f16x8 relu8(f16x8 x) {
    f16x8 z = {};
    return __builtin_elementwise_max(x, z);
}

// ===========================================================================
// XOR-slot swizzle (verified r9-r11: SQ_LDS_BANK_CONFLICT=0, coalesced):
//   LDS row-major [ROWS][32] f16; row r's global chunk c at slot c^((r>>1)&3).
//   Staging thread t: row=t>>2, fetches chunk (t&3)^((t>>3)&3) (64B window
//   per 4-lane group -> coalesced; LDS dest lane-linear for global_load_lds).
// ===========================================================================

// ---------------------------------------------------------------------------
// FUSED edge GEMM2: E2[RE,512] = relu(P[src]+Q[tgt]) @ ew2^T + eb2.
// P/Q packed in PQ[node][1024] (P cols 0:512, Q 512:1024; 0.5*eb1 folded in).
// Tile 128x256, BK=32, 4 waves, dbuf + counted vmcnt (r11 structure).
// A-operand: a 128-edge tile touches <=32 node rows (<=4 batches) -> stage
// PQl[32][32]+[32][32] (4KB) per K-step, coalesced; af = relu8(p+q) from two
// per-lane ds_read_b128 (addrs precomputed; swizzle keeps conflicts ~2-way,
// consecutive edges share src node -> P reads mostly broadcast).
// Deletes expand kernel + E1 buffer (-350MB traffic).
// ---------------------------------------------------------------------------
__global__ __launch_bounds__(256, 2)
void edge_gemm_fused(const f16* __restrict__ PQ, const f16* __restrict__ W,
                     const float* __restrict__ bias, f16* __restrict__ C)
{
    __shared__ f16 Bs[2][8192];     // [buf][256 rows][32]
    __shared__ f16 PQl[2][2048];    // [buf][ P[32][32] ; Q[32][32] ]
    const int tid  = threadIdx.x;
    const int wave = tid >> 6, lane = tid & 63;
    const int wm = wave >> 1, wn = wave & 1;
    const int lr = lane & 15, lk = lane >> 4;
    const int row0 = blockIdx.y << 7;     // edge row base
    const int col0 = blockIdx.x << 8;

    const int sc16 = (((tid & 3) ^ ((tid >> 3) & 3)) << 3);
    // B staging: granules i*256+tid (row i*64+(tid>>2), swizzled chunk)
    const f16* Wg = W + (size_t)(col0 + (tid >> 2)) * 512 + sc16;
    // P/Q staging: granule tid (<128: P row tid>>2; >=128: Q row (tid-128)>>2)
    const int b0 = row0 / 56;
    const int n0 = b0 << 3;
    const f16* PQg = PQ + (size_t)(n0 + ((tid & 127) >> 2)) * 1024
                   + ((tid >> 7) << 9) + sc16;

    // per-lane A-fragment addresses (f16 units into PQl[buf])
    int addrP[4], addrQ[4];
#pragma unroll
    for (int i = 0; i < 4; ++i) {
        int row = wm * 64 + i * 16 + lr;
        int er  = row0 + row;
        int bb  = er / 56;
        int e   = er - bb * 56;
        int r   = e / 7;
        int t2  = e - r * 7;
        int cn  = t2 + (t2 >= r ? 1 : 0);
        int pr  = ((bb - b0) << 3) + r;
        int qr  = ((bb - b0) << 3) + cn;
        addrP[i] = pr * 32 + ((lk ^ ((pr >> 1) & 3)) << 3);
        addrQ[i] = 1024 + qr * 32 + ((lk ^ ((qr >> 1) & 3)) << 3);
    }
    const int kx = (lk ^ ((lr >> 1) & 3)) << 3;   // B read slot

    f32x4 acc[4][8] = {};

#define STAGE(buf, k0)                                                        \
    do {                                                                      \
        gl_lds16(PQg + (k0), &PQl[buf][tid * 8]);                             \
        _Pragma("unroll")                                                     \
        for (int i_ = 0; i_ < 4; ++i_)                                        \
            gl_lds16(Wg + (k0) + (size_t)(i_ * 64) * 512,                     \
                     &Bs[buf][(i_ * 256 + tid) * 8]);                         \
    } while (0)

    STAGE(0, 0);                              // 5 loads in flight
    for (int t = 0; t < 16; ++t) {
        const int cur = t & 1;
        if (t < 15) {
            STAGE(cur ^ 1, (t + 1) << 5);     // +5 loads (tile t+1)
            asm volatile("s_waitcnt vmcnt(5)" ::: "memory");  // tile t landed
        } else {
            asm volatile("s_waitcnt vmcnt(0)" ::: "memory");
        }
        __builtin_amdgcn_s_barrier();
        __builtin_amdgcn_sched_barrier(0);

        f16x8 af[4], bf[8];
#pragma unroll
        for (int i = 0; i < 4; ++i) {
            f16x8 p = *(const f16x8*)&PQl[cur][addrP[i]];
            f16x8 q = *(const f16x8*)&PQl[cur][addrQ[i]];
            af[i] = relu8(p + q);
        }
#pragma unroll
        for (int i = 0; i < 8; ++i)
            bf[i] = *(const f16x8*)&Bs[cur][(wn * 128 + i * 16 + lr) * 32 + kx];
#pragma unroll
        for (int mi = 0; mi < 4; ++mi)
#pragma unroll
            for (int ni = 0; ni < 8; ++ni)
                acc[mi][ni] = __builtin_amdgcn_mfma_f32_16x16x32_f16(
                    af[mi], bf[ni], acc[mi][ni], 0, 0, 0);

        __builtin_amdgcn_sched_barrier(0);
        __builtin_amdgcn_s_barrier();
    }
#undef STAGE

#pragma unroll
    for (int mi = 0; mi < 4; ++mi) {
#pragma unroll
        for (int ni = 0; ni < 8; ++ni) {
#pragma unroll
            for (int j = 0; j < 4; ++j) {
                int r = row0 + wm * 64 + mi * 16 + lk * 4 + j;
                int c = col0 + wn * 128 + ni * 16 + lr;
                C[(size_t)r * 512 + c] = (f16)(acc[mi][ni][j] + bias[c]);
            }
        }
    }
}

// ===========================================================================
// XOR-slot swizzled 128x256 GEMM (r10/r11 verified). Used for PQ (K=128),
// ew3, nw1. launch_bounds MUST stay (256,2): (256,4) spills acc (r9).
// ===========================================================================
template<bool RELU>
__global__ __launch_bounds__(256, 2)
void gemm_swz_kernel(const f16* __restrict__ A, int lda,
                     const f16* __restrict__ W, int ldw,
                     const float* __restrict__ bias, float bscale,
                     f16* __restrict__ C, int ldc, int K)
{
    __shared__ f16 As[2][4096];
    __shared__ f16 Bs[2][8192];
    const int tid  = threadIdx.x;
    const int wave = tid >> 6, lane = tid & 63;
    const int wm = wave >> 1, wn = wave & 1;
    const int lr = lane & 15, lk = lane >> 4;
    const int row0 = blockIdx.y << 7;
    const int col0 = blockIdx.x << 8;

    const int c16 = (((tid & 3) ^ ((tid >> 3) & 3)) << 3);
    const f16* Ag = A + (size_t)(row0 + (tid >> 2)) * lda + c16;
    const f16* Wg = W + (size_t)(col0 + (tid >> 2)) * ldw + c16;
    const int kx = (lk ^ ((lr >> 1) & 3)) << 3;

    f32x4 acc[4][8] = {};

#define STAGE(buf, k0)                                                        \
    do {                                                                      \
        gl_lds16(Ag + (k0),                      &As[buf][tid * 8]);          \
        gl_lds16(Ag + (k0) + (size_t)64 * lda,   &As[buf][(tid + 256) * 8]);  \
        _Pragma("unroll")                                                     \
        for (int i_ = 0; i_ < 4; ++i_)                                        \
            gl_lds16(Wg + (k0) + (size_t)(i_ * 64) * ldw,                     \
                     &Bs[buf][(i_ * 256 + tid) * 8]);                         \
    } while (0)

    const int nt = K >> 5;
    STAGE(0, 0);
    for (int t = 0; t < nt; ++t) {
        const int cur = t & 1;
        if (t + 1 < nt) {
            STAGE(cur ^ 1, (t + 1) << 5);
            asm volatile("s_waitcnt vmcnt(6)" ::: "memory");
        } else {
            asm volatile("s_waitcnt vmcnt(0)" ::: "memory");
        }
        __builtin_amdgcn_s_barrier();
        __builtin_amdgcn_sched_barrier(0);

        f16x8 af[4], bf[8];
#pragma unroll
        for (int i = 0; i < 4; ++i)
            af[i] = *(const f16x8*)&As[cur][(wm * 64 + i * 16 + lr) * 32 + kx];
#pragma unroll
        for (int i = 0; i < 8; ++i)
            bf[i] = *(const f16x8*)&Bs[cur][(wn * 128 + i * 16 + lr) * 32 + kx];
#pragma unroll
        for (int mi = 0; mi < 4; ++mi)
#pragma unroll
            for (int ni = 0; ni < 8; ++ni)
                acc[mi][ni] = __builtin_amdgcn_mfma_f32_16x16x32_f16(
                    af[mi], bf[ni], acc[mi][ni], 0, 0, 0);

        __builtin_amdgcn_sched_barrier(0);
        __builtin_amdgcn_s_barrier();
    }
#undef STAGE

#pragma unroll
    for (int mi = 0; mi < 4; ++mi) {
#pragma unroll
        for (int ni = 0; ni < 8; ++ni) {
#pragma unroll
            for (int j = 0; j < 4; ++j) {
                int r = row0 + wm * 64 + mi * 16 + lk * 4 + j;
                int c = col0 + wn * 128 + ni * 16 + lr;
                float v = acc[mi][ni][j] + bias[c] * bscale;
                if (RELU) v = fmaxf(v, 0.0f);
                C[(size_t)r * ldc + c] = (f16)v;
            }
        }
    }
}

// ---------------------------------------------------------------------------
// Small GEMM (N=128; used once for nw3): 128x128 tile, legacy layout.
// ---------------------------------------------------------------------------
template<bool BIAS, bool RELU>
__global__ __launch_bounds__(256, 2)
void gemm_kernel(const f16* __restrict__ A, int lda,
                 const f16* __restrict__ W, int ldw,
                 const float* __restrict__ bias, float bscale,
                 f16* __restrict__ C, int ldc, int K)
{
    __shared__ f16 As[4096];
    __shared__ f16 Bs[4096];
    const int tid  = threadIdx.x;
    const int wave = tid >> 6;
    const int lane = tid & 63;
    const int wm = wave >> 1, wn = wave & 1;
    const int lr = lane & 15, lk = lane >> 4;
    const int row0 = blockIdx.y << 7;
    const int col0 = blockIdx.x << 7;

    const int srow = tid >> 2;
    const int scol = (tid & 3) << 3;
    const f16* Ag = A + (size_t)(row0 + srow) * lda + scol;
    const f16* Wg = W + (size_t)(col0 + srow) * ldw + scol;
    f16* lA0 = &As[wave * 512];
    f16* lA1 = &As[2048 + wave * 512];
    f16* lB0 = &Bs[wave * 512];
    f16* lB1 = &Bs[2048 + wave * 512];

    f32x4 acc[4][4] = {};

    for (int k0 = 0; k0 < K; k0 += 32) {
        if (k0) __syncthreads();
        gl_lds16(Ag + k0,                    lA0);
        gl_lds16(Ag + k0 + (size_t)64 * lda, lA1);
        gl_lds16(Wg + k0,                    lB0);
        gl_lds16(Wg + k0 + (size_t)64 * ldw, lB1);
        __syncthreads();

        f16x8 af[4], bf[4];
#pragma unroll
        for (int i = 0; i < 4; ++i)
            af[i] = *(const f16x8*)&As[(wm * 64 + i * 16 + lr) * 32 + lk * 8];
#pragma unroll
        for (int i = 0; i < 4; ++i)
            bf[i] = *(const f16x8*)&Bs[(wn * 64 + i * 16 + lr) * 32 + lk * 8];
#pragma unroll
        for (int mi = 0; mi < 4; ++mi)
#pragma unroll
            for (int ni = 0; ni < 4; ++ni)
                acc[mi][ni] = __builtin_amdgcn_mfma_f32_16x16x32_f16(
                    af[mi], bf[ni], acc[mi][ni], 0, 0, 0);
    }

#pragma unroll
    for (int mi = 0; mi < 4; ++mi) {
#pragma unroll
        for (int ni = 0; ni < 4; ++ni) {
#pragma unroll
            for (int j = 0; j < 4; ++j) {
                int r = row0 + wm * 64 + mi * 16 + lk * 4 + j;
                int c = col0 + wn * 64 + ni * 16 + lr;
                float v = acc[mi][ni][j];
                if (BIAS) v += bias[c] * bscale;
                if (RELU) v = fmaxf(v, 0.0f);
                C[(size_t)r * ldc + c] = (f16)v;
            }
        }
    }
}

// ---------------------------------------------------------------------------
// Fused GEMM + bias + LayerNorm + relu (node MLP layer 2). BM=64, 8 waves,
// K=512, W row-stride 512. XOR-slot swizzled staging (coalesced).
// ---------------------------------------------------------------------------
__global__ __launch_bounds__(512, 2)
void fused_gemm_ln(const f16* __restrict__ A, int lda,
                   const f16* __restrict__ W,
                   const float* __restrict__ bias,
                   const float* __restrict__ g, const float* __restrict__ b,
                   f16* __restrict__ C, int ldc)
{
    constexpr int BM = 64, NI = 4, NWN = 8;
    __shared__ f16 As[BM * 32];
    __shared__ f16 Bs[512 * 32];
    __shared__ float lnred[BM * NWN * 2];
    __shared__ float stat[BM * 2];

    const int tid  = threadIdx.x;
    const int wave = tid >> 6;
    const int lane = tid & 63;
    const int wn = wave;
    const int lr = lane & 15, lk = lane >> 4;
    const int row0 = blockIdx.x * BM;
    const int wcol0 = wn * (NI * 16);

    const int c16 = (((tid & 3) ^ ((tid >> 3) & 3)) << 3);
    const f16* Ar = A + (size_t)(row0 + (tid >> 2)) * lda + c16;
    const f16* Wr = W + (size_t)(tid >> 2) * 512 + c16;
    const int kx = (lk ^ ((lr >> 1) & 3)) << 3;

    f32x4 acc[4][NI] = {};

    for (int k0 = 0; k0 < 512; k0 += 32) {
        if (k0) __syncthreads();
#pragma unroll
        for (int i = 0; i < 4; ++i)
            gl_lds16(Wr + k0 + (size_t)(i * 128) * 512, &Bs[(i * 512 + tid) * 8]);
        if (tid < 256)
            gl_lds16(Ar + k0, &As[tid * 8]);
        __syncthreads();

        f16x8 af[4], bf[NI];
#pragma unroll
        for (int i = 0; i < 4; ++i)
            af[i] = *(const f16x8*)&As[(i * 16 + lr) * 32 + kx];
#pragma unroll
        for (int i = 0; i < NI; ++i)
            bf[i] = *(const f16x8*)&Bs[(wcol0 + i * 16 + lr) * 32 + kx];
#pragma unroll
        for (int mi = 0; mi < 4; ++mi)
#pragma unroll
            for (int ni = 0; ni < NI; ++ni)
                acc[mi][ni] = __builtin_amdgcn_mfma_f32_16x16x32_f16(
                    af[mi], bf[ni], acc[mi][ni], 0, 0, 0);
    }

    float biasv[NI], gv[NI], bv[NI];
#pragma unroll
    for (int ni = 0; ni < NI; ++ni) {
        int col = wcol0 + ni * 16 + lr;
        biasv[ni] = bias[col];
        gv[ni] = g[col];
        bv[ni] = b[col];
    }
#pragma unroll
    for (int mi = 0; mi < 4; ++mi)
#pragma unroll
        for (int ni = 0; ni < NI; ++ni)
#pragma unroll
            for (int j = 0; j < 4; ++j)
                acc[mi][ni][j] += biasv[ni];

#pragma unroll
    for (int mi = 0; mi < 4; ++mi) {
#pragma unroll
        for (int j = 0; j < 4; ++j) {
            float s = 0.f, s2 = 0.f;
#pragma unroll
            for (int ni = 0; ni < NI; ++ni) {
                float v = acc[mi][ni][j];
                s += v; s2 += v * v;
            }
#pragma unroll
            for (int o = 1; o < 16; o <<= 1) {
                s  += __shfl_xor(s,  o, 64);
                s2 += __shfl_xor(s2, o, 64);
            }
            if (lr == 0) {
                int row = mi * 16 + lk * 4 + j;
                lnred[(row * NWN + wn) * 2 + 0] = s;
                lnred[(row * NWN + wn) * 2 + 1] = s2;
            }
        }
    }
    __syncthreads();
    if (tid < BM) {
        float s = 0.f, s2 = 0.f;
#pragma unroll
        for (int w = 0; w < NWN; ++w) {
            s  += lnred[(tid * NWN + w) * 2 + 0];
            s2 += lnred[(tid * NWN + w) * 2 + 1];
        }
        float mean = s * (1.0f / 512.0f);
        float var  = fmaxf(s2 * (1.0f / 512.0f) - mean * mean, 0.0f);
        stat[tid * 2 + 0] = mean;
        stat[tid * 2 + 1] = rsqrtf(var + 1e-5f);
    }
    __syncthreads();

#pragma unroll
    for (int mi = 0; mi < 4; ++mi) {
#pragma unroll
        for (int j = 0; j < 4; ++j) {
            int row = mi * 16 + lk * 4 + j;
            float mean = stat[row * 2 + 0];
            float rstd = stat[row * 2 + 1];
            size_t gr = (size_t)(row0 + row) * ldc;
#pragma unroll
            for (int ni = 0; ni < NI; ++ni) {
                float y = (acc[mi][ni][j] - mean) * rstd * gv[ni] + bv[ni];
                C[gr + wcol0 + ni * 16 + lr] = (f16)fmaxf(y, 0.0f);
            }
        }
    }
}

// ---------------------------------------------------------------------------
// Convert fp32 -> f16. Slots strided into XCAT cols 0:128 (ldc=640).
// ew1 repacked: w_ew1x[1024][128] = [ew1[:, :128] ; ew1[:, 128:]].
// eb1x[1024] f32 = 0.5*[eb1 ; eb1].
// ---------------------------------------------------------------------------
__global__ void convert_all_kernel(
    const float* __restrict__ s0, f16* __restrict__ xcat,
    const float* __restrict__ s1, f16* __restrict__ d1,
    const float* __restrict__ s2, f16* __restrict__ d2,
    const float* __restrict__ s3, f16* __restrict__ d3,
    const float* __restrict__ s4, f16* __restrict__ d4,
    const float* __restrict__ s5, f16* __restrict__ d5,
    const float* __restrict__ s6, f16* __restrict__ d6,
    const float* __restrict__ eb1, float* __restrict__ eb1x)
{
    int q = blockIdx.x * 256 + threadIdx.x;
    if (q >= 852224) return;
    if (q < 524288) {
        const float4 v = *(const float4*)&s0[(size_t)q * 4];
        f16x4 o; o[0]=(f16)v.x; o[1]=(f16)v.y; o[2]=(f16)v.z; o[3]=(f16)v.w;
        int row = q >> 5, col = (q & 31) << 2;
        *(f16x4*)&xcat[(size_t)row * 640 + col] = o;
        return;
    }
    if (q >= 851968) {
        int i = q - 851968;
        int srcq = (i < 128) ? i : i - 128;
        const float4 v = *(const float4*)&eb1[srcq * 4];
        float4 o; o.x = 0.5f*v.x; o.y = 0.5f*v.y; o.z = 0.5f*v.z; o.w = 0.5f*v.w;
        *(float4*)&eb1x[i * 4] = o;
        return;
    }
    if (q < 557056) {
        int i = q - 524288;
        int f = i << 2;
        int n = f >> 8, c = f & 255;
        const float4 v = *(const float4*)&s1[(size_t)f];
        f16x4 o; o[0]=(f16)v.x; o[1]=(f16)v.y; o[2]=(f16)v.z; o[3]=(f16)v.w;
        int dst = (c < 128) ? n * 128 + c : (512 + n) * 128 + (c - 128);
        *(f16x4*)&d1[dst] = o;
        return;
    }
    const float* s; f16* d; int i;
    if      (q < 622592) { s = s2; d = d2; i = q - 557056; }
    else if (q < 688128) { s = s3; d = d3; i = q - 622592; }
    else if (q < 770048) { s = s4; d = d4; i = q - 688128; }
    else if (q < 835584) { s = s5; d = d5; i = q - 770048; }
    else                 { s = s6; d = d6; i = q - 835584; }
    const float4 v = *(const float4*)&s[(size_t)i * 4];
    f16x4 o; o[0]=(f16)v.x; o[1]=(f16)v.y; o[2]=(f16)v.z; o[3]=(f16)v.w;
    *(f16x4*)&d[(size_t)i * 4] = o;
}

// ---------------------------------------------------------------------------
// ln_agg: AGG[node,:] = sum_{t<7} relu(LN(E2[node*7+t,:])*g+b). 1 wave/node.
// ---------------------------------------------------------------------------
__global__ void ln_agg_kernel(const f16* __restrict__ E2,
                              const float* __restrict__ g, const float* __restrict__ b,
                              f16* __restrict__ AGG, int nodes)
{
    int gw   = (blockIdx.x * 256 + threadIdx.x) >> 6;
    int lane = threadIdx.x & 63;
    if (gw >= nodes) return;
    int bb = gw >> 3, n = gw & 7;
    const f16* base = E2 + (((size_t)(bb * 56 + n * 7)) << 9) + (lane << 3);
    f16x8 v[7];
#pragma unroll
    for (int t = 0; t < 7; ++t) v[t] = *(const f16x8*)(base + ((size_t)t << 9));
    float gv[8], bv[8], acc[8] = {};
#pragma unroll
    for (int j = 0; j < 8; ++j) {
        gv[j] = g[(lane << 3) + j];
        bv[j] = b[(lane << 3) + j];
    }
#pragma unroll
    for (int t = 0; t < 7; ++t) {
        float f[8]; float s = 0.f, s2 = 0.f;
#pragma unroll
        for (int j = 0; j < 8; ++j) { f[j] = (float)v[t][j]; s += f[j]; s2 += f[j] * f[j]; }
#pragma unroll
        for (int o = 32; o; o >>= 1) { s += __shfl_xor(s, o, 64); s2 += __shfl_xor(s2, o, 64); }
        float mean = s * (1.0f / 512.0f);
        float var  = fmaxf(s2 * (1.0f / 512.0f) - mean * mean, 0.0f);
        float rstd = rsqrtf(var + 1e-5f);
#pragma unroll
        for (int j = 0; j < 8; ++j)
            acc[j] += fmaxf((f[j] - mean) * rstd * gv[j] + bv[j], 0.0f);
    }
    f16x8 o;
#pragma unroll
    for (int j = 0; j < 8; ++j) o[j] = (f16)acc[j];
    *(f16x8*)&AGG[((size_t)gw << 9) + (lane << 3)] = o;
}

// ---------------------------------------------------------------------------
// out[b,:] = (sum_n x3[b,n,:]) @ head_w^T + head_b
// ---------------------------------------------------------------------------
__global__ void head_kernel(const f16* __restrict__ x3, const float* __restrict__ hw,
                            const float* __restrict__ hb, float* __restrict__ out)
{
    __shared__ float pooled[128];
    int b = blockIdx.x, t = threadIdx.x;   // 128 threads
    float s = 0.f;
#pragma unroll
    for (int n = 0; n < 8; ++n) s += (float)x3[(((size_t)b * 8 + n) << 7) + t];
    pooled[t] = s;
    __syncthreads();
    if (t < 12) {
        float acc = hb[t];
        for (int d = 0; d < 128; ++d) acc += pooled[d] * hw[t * 128 + d];
        out[b * 12 + t] = acc;
    }
}

// ---------------------------------------------------------------------------
extern "C" void kernel_launch(void* const* d_in, const int* in_sizes, int n_in,
                              void* d_out, int out_size, void* d_ws, size_t ws_size,
                              hipStream_t stream)
{
    const float* slots  = (const float*)d_in[0];
    const float* ew1    = (const float*)d_in[1];
    const float* eb1    = (const float*)d_in[2];
    const float* ew2    = (const float*)d_in[3];
    const float* eb2    = (const float*)d_in[4];
    const float* eln_g  = (const float*)d_in[5];
    const float* eln_b  = (const float*)d_in[6];
    const float* ew3    = (const float*)d_in[7];
    const float* eb3    = (const float*)d_in[8];
    const float* nw1    = (const float*)d_in[9];
    const float* nb1    = (const float*)d_in[10];
    const float* nw2    = (const float*)d_in[11];
    const float* nb2    = (const float*)d_in[12];
    const float* nln_g  = (const float*)d_in[13];
    const float* nln_b  = (const float*)d_in[14];
    const float* nw3    = (const float*)d_in[15];
    const float* nb3    = (const float*)d_in[16];
    const float* head_w = (const float*)d_in[17];
    const float* head_b = (const float*)d_in[18];

    char* ws = (char*)d_ws;
    f16*   XCAT    = (f16*)(ws + 0);            // 20,971,520
    f16*   w_ew1x  = (f16*)(ws + 20971520);     //   262,144  [1024][128]
    f16*   w_ew2   = (f16*)(ws + 21233664);     //   524,288
    f16*   w_ew3   = (f16*)(ws + 21757952);     //   524,288
    f16*   w_nw1   = (f16*)(ws + 22282240);     //   655,360
    f16*   w_nw2   = (f16*)(ws + 22937600);     //   524,288
    f16*   w_nw3   = (f16*)(ws + 23461888);     //   131,072
    float* eb1x    = (float*)(ws + 23592960);   //     4,096  [1024] f32
    f16*   AGG     = (f16*)(ws + 23597056);     // 16,777,216
    char*  arena   =        ws + 40374272;      // 73728*BCH bytes

    // arena = PQc(16384*BCH) + E2c(57344*BCH)  [E1 deleted]
    const size_t FIXED = 40374272ULL;
    int BCH;
    if      (ws_size >= FIXED + 73728ULL * 2048) BCH = 2048;  // 191.4 MB
    else if (ws_size >= FIXED + 73728ULL * 1024) BCH = 1024;  // 115.9 MB
    else                                         BCH = 512;   //  78.1 MB
    const int nch = 2048 / BCH;
    const int RN  = BCH * 8;    // node rows / chunk
    const int RE  = BCH * 56;   // edge rows / chunk (mult 128)

    f16* PQc = (f16*)(arena);                                  // 16384*BCH B
    f16* E2c = (f16*)(arena + (size_t)16384 * BCH);            // 57344*BCH B

    f16* X1 = AGG;
    f16* X2 = (f16*)(arena);
    f16* X3 = (f16*)(arena + 16777216);
    float* out = (float*)d_out;

    convert_all_kernel<<<dim3(3329), 256, 0, stream>>>(
        slots, XCAT, ew1, w_ew1x, ew2, w_ew2, ew3, w_ew3,
        nw1, w_nw1, nw2, w_nw2, nw3, w_nw3, eb1, eb1x);

    for (int c = 0; c < nch; ++c) {
        const f16* sc = XCAT + (size_t)c * RN * 640;
        // PQ = slots @ [ew1_P; ew1_Q]^T + 0.5*[eb1;eb1]   (one N=1024 GEMM)
        gemm_swz_kernel<false><<<dim3(4, RN/128), 256, 0, stream>>>(
            sc, 640, w_ew1x, 128, eb1x, 1.0f, PQc, 1024, 128);
        // e2 = relu(P[src]+Q[tgt]) @ ew2^T + eb2   (fused; no E1)
        edge_gemm_fused<<<dim3(2, RE/128), 256, 0, stream>>>(
            PQc, w_ew2, eb2, E2c);
        // agg = segsum(relu(LN(e2)))
        ln_agg_kernel<<<dim3(RN/4), 256, 0, stream>>>(
            E2c, eln_g, eln_b, AGG + (size_t)c * RN * 512, RN);
    }

    // xcat[:,128:640] = AGG @ ew3^T + 7*eb3   (linearity of segment-sum)
    gemm_swz_kernel<false><<<dim3(2,128), 256, 0, stream>>>(
        AGG, 512, w_ew3, 512, eb3, 7.0f, XCAT + 128, 640, 512);
    // x1 = relu(xcat @ nw1^T + nb1)
    gemm_swz_kernel<true><<<dim3(2,128), 256, 0, stream>>>(
        XCAT, 640, w_nw1, 640, nb1, 1.0f, X1, 512, 640);
    // x2 = relu(LN(x1 @ nw2^T + nb2))
    fused_gemm_ln<<<dim3(256), 512, 0, stream>>>(
        X1, 512, w_nw2, nb2, nln_g, nln_b, X2, 512);
    // x3 = relu(x2 @ nw3^T + nb3)
    gemm_kernel<true,true><<<dim3(1,128), 256, 0, stream>>>(
        X2, 512, w_nw3, 512, nb3, 1.0f, X3, 128, 512);

    head_kernel<<<dim3(2048), 128, 0, stream>>>(X3, head_w, head_b, out);
}